// Round 1
// baseline (502.564 us; speedup 1.0000x reference)
//
#include <hip/hip_runtime.h>
#include <hip/hip_fp16.h>

// Problem constants
#define NV    884736     // 96^3 voxels
#define NB    3456       // NV / 256
#define DIM   96
#define DIM2  9216       // 96*96
#define NF    6          // fields actually needed: pos1,pos2,pos3,neg0,neg1,neg2
#define VPT   4          // voxels per thread in step_kernel (96 % 4 == 0)
#define SLACK 32         // uint2 pad entries after each buffer (zeroed in init)

// Intermediate fields stored as half4 (x,y,z,pad) = 8 B/voxel.
// A z-adjacent voxel PAIR is 16 contiguous bytes -> one dwordx4 gather
// covers both z-corners of a trilinear cell. 4 gathers/sample, not 8.
//
// ONLY 6 of the 8 integrated fields are consumed by the loss:
//   F_pos[flo], flo in {1,2,3}  -> fields 0,1,2
//   F_neg[ref], ref in {0,1,2}  -> fields 3,4,5
// F_pos[0] and F_neg[3] were dead work in the previous version.

union H4 { uint2 u; __half2 h2[2]; };   // one voxel (8 B)
union H8 { uint4 u; __half2 h2[4]; };   // two z-adjacent voxels (16 B)

struct F3 { float x, y, z; };

__device__ __forceinline__ F3 lerp3(F3 a, F3 b, float t, float omt) {
    F3 r;
    r.x = a.x * omt + b.x * t;
    r.y = a.y * omt + b.y * t;
    r.z = a.z * omt + b.z * t;
    return r;
}

__device__ __forceinline__ uint2 pack_h4(float x, float y, float z) {
    H4 v;
    v.h2[0] = __floats2half2_rn(x, y);
    v.h2[1] = __floats2half2_rn(z, 0.0f);
    return v.u;
}

__device__ __forceinline__ F3 unpack_h4(uint2 raw) {
    H4 v; v.u = raw;
    float2 xy = __half22float2(v.h2[0]);
    float2 zp = __half22float2(v.h2[1]);
    F3 r; r.x = xy.x; r.y = xy.y; r.z = zp.x;
    return r;
}

// Phase-split trilinear sampling on half4 fields.
// Border semantics EXACTLY as the reference:
//   x0 = clamp((int)floor(x),0,95); x1 = min(x0+1,95); fx = x - floor(x) (unclamped)
// z edge: when z0==95 we'd need c001==c000; instead force fz=0 so the second
// voxel of the 16B pair (possibly next row / zeroed pad) is multiplied by 0.
struct TriIdx { int idx[4]; float fx, fy, fz; };

__device__ __forceinline__ TriIdx tri_prep(float x, float y, float z) {
    TriIdx t;
    float xf = floorf(x), yf = floorf(y), zf = floorf(z);
    t.fx = x - xf; t.fy = y - yf;
    float fz = z - zf;
    int x0 = (int)xf; x0 = x0 < 0 ? 0 : (x0 > DIM - 1 ? DIM - 1 : x0);
    int y0 = (int)yf; y0 = y0 < 0 ? 0 : (y0 > DIM - 1 ? DIM - 1 : y0);
    int z0 = (int)zf; z0 = z0 < 0 ? 0 : (z0 > DIM - 1 ? DIM - 1 : z0);
    int x1 = x0 + 1; if (x1 > DIM - 1) x1 = DIM - 1;
    int y1 = y0 + 1; if (y1 > DIM - 1) y1 = DIM - 1;
    t.fz = (z0 < DIM - 1) ? fz : 0.0f;
    int X0 = x0 * DIM2, X1 = x1 * DIM2;
    int Y0 = y0 * DIM,  Y1 = y1 * DIM;
    t.idx[0] = X0 + Y0 + z0;   // c00* pair
    t.idx[1] = X0 + Y1 + z0;   // c01* pair
    t.idx[2] = X1 + Y0 + z0;   // c10* pair
    t.idx[3] = X1 + Y1 + z0;   // c11* pair
    return t;
}

__device__ __forceinline__ void tri_gather(const uint2* __restrict__ f,
                                           const TriIdx& t, H8 c[4]) {
    #pragma unroll
    for (int q = 0; q < 4; q++)
        c[q].u = *(const uint4*)(f + t.idx[q]);   // 16B: voxels z0, z0+1
}

__device__ __forceinline__ F3 tri_combine(const TriIdx& t, const H8 c[4]) {
    float gz = 1.0f - t.fz, gy = 1.0f - t.fy, gx = 1.0f - t.fx;
    F3 pz[4];
    #pragma unroll
    for (int q = 0; q < 4; q++) {
        float2 xy0 = __half22float2(c[q].h2[0]);
        float2 z0p = __half22float2(c[q].h2[1]);
        float2 xy1 = __half22float2(c[q].h2[2]);
        float2 z1p = __half22float2(c[q].h2[3]);
        F3 lo; lo.x = xy0.x; lo.y = xy0.y; lo.z = z0p.x;
        F3 hi; hi.x = xy1.x; hi.y = xy1.y; hi.z = z1p.x;
        pz[q] = lerp3(lo, hi, t.fz, gz);
    }
    F3 c0 = lerp3(pz[0], pz[1], t.fy, gy);
    F3 c1 = lerp3(pz[2], pz[3], t.fy, gy);
    return lerp3(c0, c1, t.fx, gx);
}

// Init: v0 = +T/128 for transforms 1..3 -> fields 0..2,
//       v0 = -T/128 for transforms 0..2 -> fields 3..5.
// Also zeroes the loss accumulator and the 16B-overread pad of both buffers.
__global__ __launch_bounds__(256) void init_kernel(const float* __restrict__ T,
                                                   uint2* __restrict__ bufA,
                                                   uint2* __restrict__ bufB,
                                                   float* __restrict__ out) {
    int t = blockIdx.y;                       // transform 0..3
    int l = blockIdx.x * 256 + threadIdx.x;   // voxel linear index
    if (t == 0 && l == 0) out[0] = 0.0f;
    if (t == 0 && l < SLACK) {
        bufA[(size_t)NF * NV + l] = make_uint2(0u, 0u);
        bufB[(size_t)NF * NV + l] = make_uint2(0u, 0u);
    }
    const float inv = 1.0f / 128.0f;
    float vx = T[(size_t)(t * 3 + 0) * NV + l] * inv;
    float vy = T[(size_t)(t * 3 + 1) * NV + l] * inv;
    float vz = T[(size_t)(t * 3 + 2) * NV + l] * inv;
    if (t >= 1) bufA[(size_t)(t - 1) * NV + l] = pack_h4( vx,  vy,  vz);
    if (t <= 2) bufA[(size_t)(t + 3) * NV + l] = pack_h4(-vx, -vy, -vz);
}

// One scaling-and-squaring step for the 6 live fields:
//   dst = src + sample(src, grid + src).
// 4 z-consecutive voxels per thread -> 16 gathers in flight (latency hiding).
__global__ __launch_bounds__(256, 4) void step_kernel(const uint2* __restrict__ src,
                                                      uint2* __restrict__ dst) {
    int g  = blockIdx.x;
    int f  = g % NF;
    int vb = g / NF;
    const uint2* __restrict__ s = src + (size_t)f * NV;
    uint2*       __restrict__ d = dst + (size_t)f * NV;

    int l0  = (vb * 256 + (int)threadIdx.x) * VPT;
    int i   = l0 / DIM2;
    int rem = l0 - i * DIM2;
    int j   = rem / DIM;
    int k0  = rem - j * DIM;            // multiple of 4: quad never crosses a row
    float fi = (float)i, fj = (float)j;

    // own voxels: two aligned 16B loads (32B total)
    uint4 o01 = *(const uint4*)(s + l0);
    uint4 o23 = *(const uint4*)(s + l0 + 2);
    F3 v[VPT];
    v[0] = unpack_h4(make_uint2(o01.x, o01.y));
    v[1] = unpack_h4(make_uint2(o01.z, o01.w));
    v[2] = unpack_h4(make_uint2(o23.x, o23.y));
    v[3] = unpack_h4(make_uint2(o23.z, o23.w));

    TriIdx t[VPT];
    #pragma unroll
    for (int m = 0; m < VPT; m++)
        t[m] = tri_prep(fi + v[m].x, fj + v[m].y, (float)(k0 + m) + v[m].z);

    // issue ALL 16 gathers before any combine
    H8 c[VPT][4];
    #pragma unroll
    for (int m = 0; m < VPT; m++)
        tri_gather(s, t[m], c[m]);

    uint4 w01, w23;
    {
        F3 r0 = tri_combine(t[0], c[0]);
        F3 r1 = tri_combine(t[1], c[1]);
        uint2 p0 = pack_h4(v[0].x + r0.x, v[0].y + r0.y, v[0].z + r0.z);
        uint2 p1 = pack_h4(v[1].x + r1.x, v[1].y + r1.y, v[1].z + r1.z);
        w01.x = p0.x; w01.y = p0.y; w01.z = p1.x; w01.w = p1.y;
    }
    {
        F3 r2 = tri_combine(t[2], c[2]);
        F3 r3 = tri_combine(t[3], c[3]);
        uint2 p2 = pack_h4(v[2].x + r2.x, v[2].y + r2.y, v[2].z + r2.z);
        uint2 p3 = pack_h4(v[3].x + r3.x, v[3].y + r3.y, v[3].z + r3.z);
        w23.x = p2.x; w23.y = p2.y; w23.z = p3.x; w23.w = p3.y;
    }
    *(uint4*)(d + l0)     = w01;
    *(uint4*)(d + l0 + 2) = w23;
}

// Compose + residual + loss for all 6 pairs, one thread per voxel.
// Software-pipelined: 3 pair-gathers in the prologue, then
// combine(p) / issue-gather(p+3) -> steady-state 8-12 loads in flight.
__global__ __launch_bounds__(256, 4) void loss_kernel(const uint2* __restrict__ fields,
                                                      const float* __restrict__ R,
                                                      float* __restrict__ out) {
    int l = blockIdx.x * 256 + threadIdx.x;
    int k = l % DIM;
    int j = (l / DIM) % DIM;
    int i = l / DIM2;
    float fi = (float)i, fj = (float)j, fk = (float)k;

    // R is (96,96,96,3,6): 18 contiguous floats/voxel. Issue first
    // (independent, coalesced) so these loads complete before any gather.
    float rbuf[18];
    const float* Rl = R + (size_t)l * 18;
    #pragma unroll
    for (int q = 0; q < 18; q++) rbuf[q] = Rl[q];

    // F_neg for ref indices 0,1,2 -> fields 3,4,5 (coalesced)
    F3 f1c[3];
    #pragma unroll
    for (int r = 0; r < 3; r++)
        f1c[r] = unpack_h4(fields[(size_t)(3 + r) * NV + l]);

    const int REFI[6] = {0, 0, 0, 1, 1, 2};   // -> f1c index
    const int FLOF[6] = {0, 1, 2, 1, 2, 2};   // F_pos[flo] -> field flo-1

    TriIdx t[6];
    #pragma unroll
    for (int p = 0; p < 6; p++) {
        F3 f1 = f1c[REFI[p]];
        t[p] = tri_prep(fi + f1.x, fj + f1.y, fk + f1.z);
    }

    H8 c[6][4];
    #pragma unroll
    for (int p = 0; p < 3; p++)
        tri_gather(fields + (size_t)FLOF[p] * NV, t[p], c[p]);

    float acc = 0.0f;
    #pragma unroll
    for (int p = 0; p < 6; p++) {
        F3 smp = tri_combine(t[p], c[p]);     // waits only on pair p's loads
        if (p + 3 < 6)
            tri_gather(fields + (size_t)FLOF[p + 3] * NV, t[p + 3], c[p + 3]);
        F3 f1 = f1c[REFI[p]];
        float rx = f1.x + smp.x - rbuf[0 * 6 + p];
        float ry = f1.y + smp.y - rbuf[1 * 6 + p];
        float rz = f1.z + smp.z - rbuf[2 * 6 + p];
        acc += sqrtf(rx * rx + ry * ry + rz * rz);
    }

    // Block reduction: wave64 shuffle, then LDS across 4 waves, one atomic per block.
    __shared__ float wsum[4];
    int lane = threadIdx.x & 63;
    int wid  = threadIdx.x >> 6;
    #pragma unroll
    for (int off = 32; off > 0; off >>= 1)
        acc += __shfl_down(acc, off, 64);
    if (lane == 0) wsum[wid] = acc;
    __syncthreads();
    if (threadIdx.x == 0) {
        float s = wsum[0] + wsum[1] + wsum[2] + wsum[3];
        atomicAdd(out, s);
    }
}

extern "C" void kernel_launch(void* const* d_in, const int* in_sizes, int n_in,
                              void* d_out, int out_size, void* d_ws, size_t ws_size,
                              hipStream_t stream) {
    const float* T = (const float*)d_in[0];   // (4,3,96,96,96) fp32
    const float* R = (const float*)d_in[1];   // (96,96,96,3,6) fp32
    float* out = (float*)d_out;               // scalar loss

    // Workspace: two ping-pong buffers of 6 half4 fields.
    // Each buffer: 6 * 884736 * 8 B = 42.5 MB; +SLACK uint2 pad (zeroed) for
    // the 16B pair-gather that can read 8B past the last voxel.
    uint2* bufA = (uint2*)d_ws;
    uint2* bufB = bufA + (size_t)NF * NV + SLACK;

    dim3 blk(256);
    init_kernel<<<dim3(NB, 4), blk, 0, stream>>>(T, bufA, bufB, out);

    uint2* src = bufA;
    uint2* dst = bufB;
    const int step_blocks = (NV / (256 * VPT)) * NF;   // 864 * 6 = 5184
    for (int s = 0; s < 7; s++) {
        step_kernel<<<step_blocks, blk, 0, stream>>>(src, dst);
        uint2* tmp = src; src = dst; dst = tmp;
    }
    // After 7 steps (odd), final fields are in bufB == src.
    loss_kernel<<<NB, blk, 0, stream>>>(src, R, out);
}

// Round 2
// 350.168 us; speedup vs baseline: 1.4352x; 1.4352x over previous
//
#include <hip/hip_runtime.h>
#include <hip/hip_fp16.h>

// Problem constants
#define NV    884736     // 96^3 voxels
#define NB    3456       // NV / 256
#define DIM   96
#define DIM2  9216       // 96*96
#define NF    6          // fields actually needed: pos1,pos2,pos3,neg0,neg1,neg2
#define VPT   2          // voxels per thread in step_kernel (z-pair; 96 even)
#define SLACK 32         // uint2 pad entries after each buffer (zeroed in init)

// Intermediate fields stored as half4 (x,y,z,pad) = 8 B/voxel.
// A z-adjacent voxel PAIR is 16 contiguous bytes -> one dwordx4 gather
// covers both z-corners of a trilinear cell. 4 gathers/sample, not 8.
//
// ONLY 6 of the 8 integrated fields are consumed by the loss:
//   F_pos[flo], flo in {1,2,3}  -> fields 0,1,2
//   F_neg[ref], ref in {0,1,2}  -> fields 3,4,5
//
// XCD locality (round-1 lesson): gathers are served by the per-XCD 4 MB L2.
// Under round-robin dispatch (XCD = blockIdx.x % 8), we give each XCD a
// CONTIGUOUS chunk of the (field, voxel-block) work list so each XCD's L2
// holds slabs of at most 2 fields. Spraying fields across XCDs (f = b % 6)
// cost ~1.7x in step latency in round 1.

union H4 { uint2 u; __half2 h2[2]; };   // one voxel (8 B)
union H8 { uint4 u; __half2 h2[4]; };   // two z-adjacent voxels (16 B)

struct F3 { float x, y, z; };

__device__ __forceinline__ F3 lerp3(F3 a, F3 b, float t, float omt) {
    F3 r;
    r.x = a.x * omt + b.x * t;
    r.y = a.y * omt + b.y * t;
    r.z = a.z * omt + b.z * t;
    return r;
}

__device__ __forceinline__ uint2 pack_h4(float x, float y, float z) {
    H4 v;
    v.h2[0] = __floats2half2_rn(x, y);
    v.h2[1] = __floats2half2_rn(z, 0.0f);
    return v.u;
}

__device__ __forceinline__ F3 unpack_h4(uint2 raw) {
    H4 v; v.u = raw;
    float2 xy = __half22float2(v.h2[0]);
    float2 zp = __half22float2(v.h2[1]);
    F3 r; r.x = xy.x; r.y = xy.y; r.z = zp.x;
    return r;
}

// Phase-split trilinear sampling on half4 fields.
// Border semantics EXACTLY as the reference:
//   x0 = clamp((int)floor(x),0,95); x1 = min(x0+1,95); fx = x - floor(x) (unclamped)
// z edge: when z0==95 we'd need c001==c000; instead force fz=0 so the second
// voxel of the 16B pair (possibly next row / zeroed pad) is multiplied by 0.
struct TriIdx { int idx[4]; float fx, fy, fz; };

__device__ __forceinline__ TriIdx tri_prep(float x, float y, float z) {
    TriIdx t;
    float xf = floorf(x), yf = floorf(y), zf = floorf(z);
    t.fx = x - xf; t.fy = y - yf;
    float fz = z - zf;
    int x0 = (int)xf; x0 = x0 < 0 ? 0 : (x0 > DIM - 1 ? DIM - 1 : x0);
    int y0 = (int)yf; y0 = y0 < 0 ? 0 : (y0 > DIM - 1 ? DIM - 1 : y0);
    int z0 = (int)zf; z0 = z0 < 0 ? 0 : (z0 > DIM - 1 ? DIM - 1 : z0);
    int x1 = x0 + 1; if (x1 > DIM - 1) x1 = DIM - 1;
    int y1 = y0 + 1; if (y1 > DIM - 1) y1 = DIM - 1;
    t.fz = (z0 < DIM - 1) ? fz : 0.0f;
    int X0 = x0 * DIM2, X1 = x1 * DIM2;
    int Y0 = y0 * DIM,  Y1 = y1 * DIM;
    t.idx[0] = X0 + Y0 + z0;   // c00* pair
    t.idx[1] = X0 + Y1 + z0;   // c01* pair
    t.idx[2] = X1 + Y0 + z0;   // c10* pair
    t.idx[3] = X1 + Y1 + z0;   // c11* pair
    return t;
}

__device__ __forceinline__ void tri_gather(const uint2* __restrict__ f,
                                           const TriIdx& t, H8 c[4]) {
    #pragma unroll
    for (int q = 0; q < 4; q++)
        c[q].u = *(const uint4*)(f + t.idx[q]);   // 16B: voxels z0, z0+1
}

__device__ __forceinline__ F3 tri_combine(const TriIdx& t, const H8 c[4]) {
    float gz = 1.0f - t.fz, gy = 1.0f - t.fy, gx = 1.0f - t.fx;
    F3 pz[4];
    #pragma unroll
    for (int q = 0; q < 4; q++) {
        float2 xy0 = __half22float2(c[q].h2[0]);
        float2 z0p = __half22float2(c[q].h2[1]);
        float2 xy1 = __half22float2(c[q].h2[2]);
        float2 z1p = __half22float2(c[q].h2[3]);
        F3 lo; lo.x = xy0.x; lo.y = xy0.y; lo.z = z0p.x;
        F3 hi; hi.x = xy1.x; hi.y = xy1.y; hi.z = z1p.x;
        pz[q] = lerp3(lo, hi, t.fz, gz);
    }
    F3 c0 = lerp3(pz[0], pz[1], t.fy, gy);
    F3 c1 = lerp3(pz[2], pz[3], t.fy, gy);
    return lerp3(c0, c1, t.fx, gx);
}

// Init: v0 = +T/128 for transforms 1..3 -> fields 0..2,
//       v0 = -T/128 for transforms 0..2 -> fields 3..5.
// Also zeroes the loss accumulator and the 16B-overread pad of both buffers.
__global__ __launch_bounds__(256) void init_kernel(const float* __restrict__ T,
                                                   uint2* __restrict__ bufA,
                                                   uint2* __restrict__ bufB,
                                                   float* __restrict__ out) {
    int t = blockIdx.y;                       // transform 0..3
    int l = blockIdx.x * 256 + threadIdx.x;   // voxel linear index
    if (t == 0 && l == 0) out[0] = 0.0f;
    if (t == 0 && l < SLACK) {
        bufA[(size_t)NF * NV + l] = make_uint2(0u, 0u);
        bufB[(size_t)NF * NV + l] = make_uint2(0u, 0u);
    }
    const float inv = 1.0f / 128.0f;
    float vx = T[(size_t)(t * 3 + 0) * NV + l] * inv;
    float vy = T[(size_t)(t * 3 + 1) * NV + l] * inv;
    float vz = T[(size_t)(t * 3 + 2) * NV + l] * inv;
    if (t >= 1) bufA[(size_t)(t - 1) * NV + l] = pack_h4( vx,  vy,  vz);
    if (t <= 2) bufA[(size_t)(t + 3) * NV + l] = pack_h4(-vx, -vy, -vz);
}

// One scaling-and-squaring step for the 6 live fields:
//   dst = src + sample(src, grid + src).
// 2 z-consecutive voxels per thread -> 8 gathers in flight, ~90 VGPR (no spill).
// Work list: w in [0, 6*1728); field = w/1728, vb = w%1728.
// XCD-chunked swizzle: XCD x runs contiguous w in [x*1296, (x+1)*1296) ->
// each XCD touches <=2 fields with contiguous voxel ranges (L2 locality).
#define STEP_VB   (NV / (256 * VPT))      // 1728 voxel-blocks per field
#define STEP_W    (STEP_VB * NF)          // 10368 work units
#define STEP_CHK  (STEP_W / 8)            // 1296 per XCD
__global__ __launch_bounds__(256) void step_kernel(const uint2* __restrict__ src,
                                                   uint2* __restrict__ dst) {
    int b   = blockIdx.x;
    int w   = (b & 7) * STEP_CHK + (b >> 3);
    int f   = w / STEP_VB;
    int vb  = w - f * STEP_VB;
    const uint2* __restrict__ s = src + (size_t)f * NV;
    uint2*       __restrict__ d = dst + (size_t)f * NV;

    int l0  = (vb * 256 + (int)threadIdx.x) * VPT;
    int i   = l0 / DIM2;
    int rem = l0 - i * DIM2;
    int j   = rem / DIM;
    int k0  = rem - j * DIM;            // even: z-pair never crosses a row
    float fi = (float)i, fj = (float)j;

    // own voxels: one aligned 16B load
    uint4 o01 = *(const uint4*)(s + l0);
    F3 v[VPT];
    v[0] = unpack_h4(make_uint2(o01.x, o01.y));
    v[1] = unpack_h4(make_uint2(o01.z, o01.w));

    TriIdx t[VPT];
    #pragma unroll
    for (int m = 0; m < VPT; m++)
        t[m] = tri_prep(fi + v[m].x, fj + v[m].y, (float)(k0 + m) + v[m].z);

    // issue all 8 gathers before any combine
    H8 c[VPT][4];
    #pragma unroll
    for (int m = 0; m < VPT; m++)
        tri_gather(s, t[m], c[m]);

    F3 r0 = tri_combine(t[0], c[0]);
    F3 r1 = tri_combine(t[1], c[1]);
    uint2 p0 = pack_h4(v[0].x + r0.x, v[0].y + r0.y, v[0].z + r0.z);
    uint2 p1 = pack_h4(v[1].x + r1.x, v[1].y + r1.y, v[1].z + r1.z);
    uint4 wv; wv.x = p0.x; wv.y = p0.y; wv.z = p1.x; wv.w = p1.y;
    *(uint4*)(d + l0) = wv;
}

// Compose + residual + loss for all 6 pairs, one thread per voxel,
// two pairs in flight (round-0 structure: proven 63 us; 3-in-flight regressed).
__global__ __launch_bounds__(256) void loss_kernel(const uint2* __restrict__ fields,
                                                   const float* __restrict__ R,
                                                   float* __restrict__ out) {
    int l = blockIdx.x * 256 + threadIdx.x;
    int k = l % DIM;
    int j = (l / DIM) % DIM;
    int i = l / DIM2;
    float fi = (float)i, fj = (float)j, fk = (float)k;

    // F_neg for ref indices 0,1,2 -> fields 3,4,5
    F3 f1c[3];
    #pragma unroll
    for (int r = 0; r < 3; r++)
        f1c[r] = unpack_h4(fields[(size_t)(3 + r) * NV + l]);

    // R is (96,96,96,3,6): voxel-major, then channel, then pair. 18 floats/voxel.
    float rbuf[18];
    const float* Rl = R + (size_t)l * 18;
    #pragma unroll
    for (int q = 0; q < 18; q++) rbuf[q] = Rl[q];

    const int REFI[6] = {0, 0, 0, 1, 1, 2};   // -> f1c index
    const int FLOF[6] = {0, 1, 2, 1, 2, 2};   // F_pos[flo] -> field flo-1

    float acc = 0.0f;
    #pragma unroll
    for (int p = 0; p < 6; p += 2) {
        F3 f1a = f1c[REFI[p]];
        F3 f1b = f1c[REFI[p + 1]];
        const uint2* __restrict__ f2a = fields + (size_t)FLOF[p]     * NV;
        const uint2* __restrict__ f2b = fields + (size_t)FLOF[p + 1] * NV;
        TriIdx ta = tri_prep(fi + f1a.x, fj + f1a.y, fk + f1a.z);
        TriIdx tb = tri_prep(fi + f1b.x, fj + f1b.y, fk + f1b.z);
        H8 ca[4], cb[4];
        tri_gather(f2a, ta, ca);
        tri_gather(f2b, tb, cb);
        F3 sa = tri_combine(ta, ca);
        F3 sb = tri_combine(tb, cb);
        float rx = f1a.x + sa.x - rbuf[0 * 6 + p];
        float ry = f1a.y + sa.y - rbuf[1 * 6 + p];
        float rz = f1a.z + sa.z - rbuf[2 * 6 + p];
        acc += sqrtf(rx * rx + ry * ry + rz * rz);
        rx = f1b.x + sb.x - rbuf[0 * 6 + p + 1];
        ry = f1b.y + sb.y - rbuf[1 * 6 + p + 1];
        rz = f1b.z + sb.z - rbuf[2 * 6 + p + 1];
        acc += sqrtf(rx * rx + ry * ry + rz * rz);
    }

    // Block reduction: wave64 shuffle, then LDS across 4 waves, one atomic per block.
    __shared__ float wsum[4];
    int lane = threadIdx.x & 63;
    int wid  = threadIdx.x >> 6;
    #pragma unroll
    for (int off = 32; off > 0; off >>= 1)
        acc += __shfl_down(acc, off, 64);
    if (lane == 0) wsum[wid] = acc;
    __syncthreads();
    if (threadIdx.x == 0) {
        float s = wsum[0] + wsum[1] + wsum[2] + wsum[3];
        atomicAdd(out, s);
    }
}

extern "C" void kernel_launch(void* const* d_in, const int* in_sizes, int n_in,
                              void* d_out, int out_size, void* d_ws, size_t ws_size,
                              hipStream_t stream) {
    const float* T = (const float*)d_in[0];   // (4,3,96,96,96) fp32
    const float* R = (const float*)d_in[1];   // (96,96,96,3,6) fp32
    float* out = (float*)d_out;               // scalar loss

    // Workspace: two ping-pong buffers of 6 half4 fields.
    // Each buffer: 6 * 884736 * 8 B = 42.5 MB; +SLACK uint2 pad (zeroed) for
    // the 16B pair-gather that can read 8B past the last voxel.
    uint2* bufA = (uint2*)d_ws;
    uint2* bufB = bufA + (size_t)NF * NV + SLACK;

    dim3 blk(256);
    init_kernel<<<dim3(NB, 4), blk, 0, stream>>>(T, bufA, bufB, out);

    uint2* src = bufA;
    uint2* dst = bufB;
    for (int s = 0; s < 7; s++) {
        step_kernel<<<STEP_W, blk, 0, stream>>>(src, dst);
        uint2* tmp = src; src = dst; dst = tmp;
    }
    // After 7 steps (odd), final fields are in bufB == src.
    loss_kernel<<<NB, blk, 0, stream>>>(src, R, out);
}

// Round 3
// 348.020 us; speedup vs baseline: 1.4441x; 1.0062x over previous
//
#include <hip/hip_runtime.h>
#include <hip/hip_fp16.h>

// Problem constants
#define NV    884736     // 96^3 voxels
#define NB    3456       // NV / 256
#define DIM   96
#define DIM2  9216       // 96*96
#define NF    6          // fields actually needed: pos1,pos2,pos3,neg0,neg1,neg2
#define SLACK 32         // uint2 pad entries after each buffer (zeroed in init)

// Intermediate fields stored as half4 (x,y,z,pad) = 8 B/voxel.
// A z-adjacent voxel PAIR is 16 contiguous bytes -> one dwordx4 gather
// covers both z-corners of a trilinear cell. 4 gathers/sample, not 8.
//
// ONLY 6 of the 8 integrated fields are consumed by the loss:
//   F_pos[flo], flo in {1,2,3}  -> fields 0,1,2
//   F_neg[ref], ref in {0,1,2}  -> fields 3,4,5
//
// XCD locality: gathers are served by the per-XCD 4 MB L2. Under round-robin
// HW dispatch (XCD = blockIdx.x % 8) we remap the block index so each XCD
// processes a CONTIGUOUS chunk of work -> small active gather slab per L2.
// Round-1 lesson: spraying fields across XCDs cost ~1.7x in step latency.
// Round-2 lesson: VPT=2 (8 in-flight gathers/thread) raises VGPR and cuts
// resident waves -- per-sample rate DROPPED vs VPT=1. Waves are the better
// latency-hiding currency here; keep VPT=1.

union H4 { uint2 u; __half2 h2[2]; };   // one voxel (8 B)
union H8 { uint4 u; __half2 h2[4]; };   // two z-adjacent voxels (16 B)

struct F3 { float x, y, z; };

__device__ __forceinline__ F3 lerp3(F3 a, F3 b, float t, float omt) {
    F3 r;
    r.x = a.x * omt + b.x * t;
    r.y = a.y * omt + b.y * t;
    r.z = a.z * omt + b.z * t;
    return r;
}

__device__ __forceinline__ uint2 pack_h4(float x, float y, float z) {
    H4 v;
    v.h2[0] = __floats2half2_rn(x, y);
    v.h2[1] = __floats2half2_rn(z, 0.0f);
    return v.u;
}

__device__ __forceinline__ F3 unpack_h4(uint2 raw) {
    H4 v; v.u = raw;
    float2 xy = __half22float2(v.h2[0]);
    float2 zp = __half22float2(v.h2[1]);
    F3 r; r.x = xy.x; r.y = xy.y; r.z = zp.x;
    return r;
}

// Phase-split trilinear sampling on half4 fields.
// Border semantics EXACTLY as the reference:
//   x0 = clamp((int)floor(x),0,95); x1 = min(x0+1,95); fx = x - floor(x) (unclamped)
// z edge: when z0==95 we'd need c001==c000; instead force fz=0 so the second
// voxel of the 16B pair (possibly next row / zeroed pad) is multiplied by 0.
struct TriIdx { int idx[4]; float fx, fy, fz; };

__device__ __forceinline__ TriIdx tri_prep(float x, float y, float z) {
    TriIdx t;
    float xf = floorf(x), yf = floorf(y), zf = floorf(z);
    t.fx = x - xf; t.fy = y - yf;
    float fz = z - zf;
    int x0 = (int)xf; x0 = x0 < 0 ? 0 : (x0 > DIM - 1 ? DIM - 1 : x0);
    int y0 = (int)yf; y0 = y0 < 0 ? 0 : (y0 > DIM - 1 ? DIM - 1 : y0);
    int z0 = (int)zf; z0 = z0 < 0 ? 0 : (z0 > DIM - 1 ? DIM - 1 : z0);
    int x1 = x0 + 1; if (x1 > DIM - 1) x1 = DIM - 1;
    int y1 = y0 + 1; if (y1 > DIM - 1) y1 = DIM - 1;
    t.fz = (z0 < DIM - 1) ? fz : 0.0f;
    int X0 = x0 * DIM2, X1 = x1 * DIM2;
    int Y0 = y0 * DIM,  Y1 = y1 * DIM;
    t.idx[0] = X0 + Y0 + z0;   // c00* pair
    t.idx[1] = X0 + Y1 + z0;   // c01* pair
    t.idx[2] = X1 + Y0 + z0;   // c10* pair
    t.idx[3] = X1 + Y1 + z0;   // c11* pair
    return t;
}

__device__ __forceinline__ void tri_gather(const uint2* __restrict__ f,
                                           const TriIdx& t, H8 c[4]) {
    #pragma unroll
    for (int q = 0; q < 4; q++)
        c[q].u = *(const uint4*)(f + t.idx[q]);   // 16B: voxels z0, z0+1
}

__device__ __forceinline__ F3 tri_combine(const TriIdx& t, const H8 c[4]) {
    float gz = 1.0f - t.fz, gy = 1.0f - t.fy, gx = 1.0f - t.fx;
    F3 pz[4];
    #pragma unroll
    for (int q = 0; q < 4; q++) {
        float2 xy0 = __half22float2(c[q].h2[0]);
        float2 z0p = __half22float2(c[q].h2[1]);
        float2 xy1 = __half22float2(c[q].h2[2]);
        float2 z1p = __half22float2(c[q].h2[3]);
        F3 lo; lo.x = xy0.x; lo.y = xy0.y; lo.z = z0p.x;
        F3 hi; hi.x = xy1.x; hi.y = xy1.y; hi.z = z1p.x;
        pz[q] = lerp3(lo, hi, t.fz, gz);
    }
    F3 c0 = lerp3(pz[0], pz[1], t.fy, gy);
    F3 c1 = lerp3(pz[2], pz[3], t.fy, gy);
    return lerp3(c0, c1, t.fx, gx);
}

// Init: v0 = +T/128 for transforms 1..3 -> fields 0..2,
//       v0 = -T/128 for transforms 0..2 -> fields 3..5.
// Also zeroes the loss accumulator and the 16B-overread pad of both buffers.
__global__ __launch_bounds__(256) void init_kernel(const float* __restrict__ T,
                                                   uint2* __restrict__ bufA,
                                                   uint2* __restrict__ bufB,
                                                   float* __restrict__ out) {
    int t = blockIdx.y;                       // transform 0..3
    int l = blockIdx.x * 256 + threadIdx.x;   // voxel linear index
    if (t == 0 && l == 0) out[0] = 0.0f;
    if (t == 0 && l < SLACK) {
        bufA[(size_t)NF * NV + l] = make_uint2(0u, 0u);
        bufB[(size_t)NF * NV + l] = make_uint2(0u, 0u);
    }
    const float inv = 1.0f / 128.0f;
    float vx = T[(size_t)(t * 3 + 0) * NV + l] * inv;
    float vy = T[(size_t)(t * 3 + 1) * NV + l] * inv;
    float vz = T[(size_t)(t * 3 + 2) * NV + l] * inv;
    if (t >= 1) bufA[(size_t)(t - 1) * NV + l] = pack_h4( vx,  vy,  vz);
    if (t <= 2) bufA[(size_t)(t + 3) * NV + l] = pack_h4(-vx, -vy, -vz);
}

// One scaling-and-squaring step for the 6 live fields:
//   dst = src + sample(src, grid + src).
// VPT=1 (round-0's best-measured per-sample structure: 4 gathers in flight,
// low VGPR, max resident waves). XCD-chunked bijective swizzle:
// work w in [0, 6*3456); field = w/3456, vb = w%3456; XCD x runs the
// contiguous range [x*2592, (x+1)*2592) -> <=2 fields, small slab per L2.
#define STEP_VB   NB                      // 3456 voxel-blocks per field
#define STEP_W    (STEP_VB * NF)          // 20736 work units
#define STEP_CHK  (STEP_W / 8)            // 2592 per XCD
__global__ __launch_bounds__(256) void step_kernel(const uint2* __restrict__ src,
                                                   uint2* __restrict__ dst) {
    int b   = blockIdx.x;
    int w   = (b & 7) * STEP_CHK + (b >> 3);
    int f   = w / STEP_VB;
    int vb  = w - f * STEP_VB;
    const uint2* __restrict__ s = src + (size_t)f * NV;
    uint2*       __restrict__ d = dst + (size_t)f * NV;

    int l   = vb * 256 + threadIdx.x;
    int i   = l / DIM2;
    int rem = l - i * DIM2;
    int j   = rem / DIM;
    int k   = rem - j * DIM;

    F3 v = unpack_h4(s[l]);
    TriIdx t = tri_prep((float)i + v.x, (float)j + v.y, (float)k + v.z);
    H8 c[4];
    tri_gather(s, t, c);
    F3 smp = tri_combine(t, c);
    d[l] = pack_h4(v.x + smp.x, v.y + smp.y, v.z + smp.z);
}

// Compose + residual + loss for all 6 pairs, one thread per voxel,
// two pairs in flight (3-in-flight thrashed L2 in round 1: FETCH +21 MB).
// XCD-chunked: XCD x owns contiguous voxel-blocks [x*432, (x+1)*432) -> its
// gather slab = 3 F_pos fields x ~1/8 of the volume ~ 2.8 MB -> fits 4 MB L2.
__global__ __launch_bounds__(256) void loss_kernel(const uint2* __restrict__ fields,
                                                   const float* __restrict__ R,
                                                   float* __restrict__ out) {
    int b = blockIdx.x;
    int vb = (b & 7) * (NB / 8) + (b >> 3);   // bijective chunk swizzle
    int l = vb * 256 + threadIdx.x;
    int k = l % DIM;
    int j = (l / DIM) % DIM;
    int i = l / DIM2;
    float fi = (float)i, fj = (float)j, fk = (float)k;

    // F_neg for ref indices 0,1,2 -> fields 3,4,5
    F3 f1c[3];
    #pragma unroll
    for (int r = 0; r < 3; r++)
        f1c[r] = unpack_h4(fields[(size_t)(3 + r) * NV + l]);

    // R is (96,96,96,3,6): voxel-major, then channel, then pair. 18 floats/voxel.
    float rbuf[18];
    const float* Rl = R + (size_t)l * 18;
    #pragma unroll
    for (int q = 0; q < 18; q++) rbuf[q] = Rl[q];

    const int REFI[6] = {0, 0, 0, 1, 1, 2};   // -> f1c index
    const int FLOF[6] = {0, 1, 2, 1, 2, 2};   // F_pos[flo] -> field flo-1

    float acc = 0.0f;
    #pragma unroll
    for (int p = 0; p < 6; p += 2) {
        F3 f1a = f1c[REFI[p]];
        F3 f1b = f1c[REFI[p + 1]];
        const uint2* __restrict__ f2a = fields + (size_t)FLOF[p]     * NV;
        const uint2* __restrict__ f2b = fields + (size_t)FLOF[p + 1] * NV;
        TriIdx ta = tri_prep(fi + f1a.x, fj + f1a.y, fk + f1a.z);
        TriIdx tb = tri_prep(fi + f1b.x, fj + f1b.y, fk + f1b.z);
        H8 ca[4], cb[4];
        tri_gather(f2a, ta, ca);
        tri_gather(f2b, tb, cb);
        F3 sa = tri_combine(ta, ca);
        F3 sb = tri_combine(tb, cb);
        float rx = f1a.x + sa.x - rbuf[0 * 6 + p];
        float ry = f1a.y + sa.y - rbuf[1 * 6 + p];
        float rz = f1a.z + sa.z - rbuf[2 * 6 + p];
        acc += sqrtf(rx * rx + ry * ry + rz * rz);
        rx = f1b.x + sb.x - rbuf[0 * 6 + p + 1];
        ry = f1b.y + sb.y - rbuf[1 * 6 + p + 1];
        rz = f1b.z + sb.z - rbuf[2 * 6 + p + 1];
        acc += sqrtf(rx * rx + ry * ry + rz * rz);
    }

    // Block reduction: wave64 shuffle, then LDS across 4 waves, one atomic per block.
    __shared__ float wsum[4];
    int lane = threadIdx.x & 63;
    int wid  = threadIdx.x >> 6;
    #pragma unroll
    for (int off = 32; off > 0; off >>= 1)
        acc += __shfl_down(acc, off, 64);
    if (lane == 0) wsum[wid] = acc;
    __syncthreads();
    if (threadIdx.x == 0) {
        float s = wsum[0] + wsum[1] + wsum[2] + wsum[3];
        atomicAdd(out, s);
    }
}

extern "C" void kernel_launch(void* const* d_in, const int* in_sizes, int n_in,
                              void* d_out, int out_size, void* d_ws, size_t ws_size,
                              hipStream_t stream) {
    const float* T = (const float*)d_in[0];   // (4,3,96,96,96) fp32
    const float* R = (const float*)d_in[1];   // (96,96,96,3,6) fp32
    float* out = (float*)d_out;               // scalar loss

    // Workspace: two ping-pong buffers of 6 half4 fields.
    // Each buffer: 6 * 884736 * 8 B = 42.5 MB; +SLACK uint2 pad (zeroed) for
    // the 16B pair-gather that can read 8B past the last voxel.
    uint2* bufA = (uint2*)d_ws;
    uint2* bufB = bufA + (size_t)NF * NV + SLACK;

    dim3 blk(256);
    init_kernel<<<dim3(NB, 4), blk, 0, stream>>>(T, bufA, bufB, out);

    uint2* src = bufA;
    uint2* dst = bufB;
    for (int s = 0; s < 7; s++) {
        step_kernel<<<STEP_W, blk, 0, stream>>>(src, dst);
        uint2* tmp = src; src = dst; dst = tmp;
    }
    // After 7 steps (odd), final fields are in bufB == src.
    loss_kernel<<<NB, blk, 0, stream>>>(src, R, out);
}